// Round 5
// baseline (722.996 us; speedup 1.0000x reference)
//
#include <hip/hip_runtime.h>

#define N_NODES 50000
#define N_EDGES 1600000
#define NB 128
#define GB 782            // ceil(N/64)
#define P1B 196           // pass-1 blocks, 8192 edges each
#define P1E 8192
#define NBUCK 196         // dst >> 8 (256 nodes per bucket)

__device__ __forceinline__ unsigned short f2bf(float f) {
    unsigned u = __float_as_uint(f);
    unsigned r = (u + 0x7FFFu + ((u >> 16) & 1u)) >> 16;   // RNE
    return (unsigned short)r;
}
__device__ __forceinline__ float bf2f(unsigned short u) {
    return __uint_as_float(((unsigned)u) << 16);
}

// ---------- CSR build: two-phase radix partition ----------
// pass 1a: per-block histogram over 196 dst-buckets
__global__ __launch_bounds__(256) void k_p1hist(
    const int* __restrict__ dst, int* __restrict__ gcount) {
    __shared__ int hist[NBUCK];
    int tid = threadIdx.x;
    if (tid < NBUCK) hist[tid] = 0;
    __syncthreads();
    int base = blockIdx.x * P1E;
    for (int k = 0; k < P1E; k += 256) {
        int e = base + k + tid;
        if (e < N_EDGES) atomicAdd(&hist[dst[e] >> 8], 1);
    }
    __syncthreads();
    if (tid < NBUCK) gcount[tid * P1B + blockIdx.x] = hist[tid];
}

// pass 1b: one block turns gcount (bucket-major counts) into exclusive offsets in place
__global__ __launch_bounds__(256) void k_p1scan(
    int* __restrict__ gcount, int* __restrict__ row_ptr) {
    __shared__ int part[256];
    const int TOT = NBUCK * P1B;   // 38416
    const int PER = 151;           // 256*151 >= TOT
    int t = threadIdx.x;
    int b0 = t * PER, b1 = b0 + PER; if (b1 > TOT) b1 = TOT;
    int s = 0;
    for (int i = b0; i < b1; ++i) s += gcount[i];
    part[t] = s;
    __syncthreads();
    for (int off = 1; off < 256; off <<= 1) {
        int x = part[t];
        int y = (t >= off) ? part[t - off] : 0;
        __syncthreads();
        part[t] = x + y;
        __syncthreads();
    }
    int run = part[t] - s;
    for (int i = b0; i < b1; ++i) { int v = gcount[i]; gcount[i] = run; run += v; }
    if (t == 255) row_ptr[N_NODES] = part[255];   // = E
}

// pass 1c: scatter edges into bucket regions; payload = (dst_low8 << 16) | src
__global__ __launch_bounds__(256) void k_p1scat(
    const int* __restrict__ src, const int* __restrict__ dst,
    const int* __restrict__ goff, unsigned* __restrict__ tmp) {
    __shared__ int cur[NBUCK];
    int tid = threadIdx.x;
    if (tid < NBUCK) cur[tid] = goff[tid * P1B + blockIdx.x];
    __syncthreads();
    int base = blockIdx.x * P1E;
    for (int k = 0; k < P1E; k += 256) {
        int e = base + k + tid;
        if (e < N_EDGES) {
            int d = dst[e];
            int pos = atomicAdd(&cur[d >> 8], 1);
            tmp[pos] = ((unsigned)(d & 255) << 16) | (unsigned)src[e];
        }
    }
}

// pass 2: one block per bucket -> per-node row_ptr + csr_src (single-owner writes)
__global__ __launch_bounds__(256) void k_p2(
    const unsigned* __restrict__ tmp, const int* __restrict__ goff,
    int* __restrict__ row_ptr, unsigned short* __restrict__ csr_src) {
    __shared__ int nh[256];
    __shared__ int ps[256];
    int b = blockIdx.x, tid = threadIdx.x;
    int base = goff[b * P1B];
    int endv = (b == NBUCK - 1) ? N_EDGES : goff[(b + 1) * P1B];
    int cnt = endv - base;
    nh[tid] = 0;
    __syncthreads();
    for (int i = tid; i < cnt; i += 256)
        atomicAdd(&nh[tmp[base + i] >> 16], 1);
    __syncthreads();
    int deg = nh[tid];
    ps[tid] = deg;
    __syncthreads();
    for (int off = 1; off < 256; off <<= 1) {
        int x = ps[tid];
        int y = (tid >= off) ? ps[tid - off] : 0;
        __syncthreads();
        ps[tid] = x + y;
        __syncthreads();
    }
    int ex = ps[tid] - deg;
    int node = (b << 8) + tid;
    if (node < N_NODES) row_ptr[node] = base + ex;
    __syncthreads();
    nh[tid] = ex;   // cursor
    __syncthreads();
    for (int i = tid; i < cnt; i += 256) {
        unsigned u = tmp[base + i];
        int pos = atomicAdd(&nh[u >> 16], 1);
        csr_src[base + pos] = (unsigned short)(u & 0xFFFFu);
    }
}

// vn = pooled = broadcast(vn_emb)
__global__ __launch_bounds__(256) void k_vn_init(
    const float* __restrict__ vn_emb, float* __restrict__ vn,
    float* __restrict__ pooled) {
    int t = blockIdx.x * 256 + threadIdx.x;
    float v = vn_emb[t & 63];
    vn[t] = v;
    pooled[t] = v;
}

// Fused: h += vn[batch]; out (init/accum); rbuf = bf16(relu(h)); pooled += seg_sum(h)
__global__ __launch_bounds__(256) void k_pre(
    float* __restrict__ h, const float* __restrict__ vn,
    const int* __restrict__ batch_id, float* __restrict__ out,
    unsigned short* __restrict__ rbuf, float* __restrict__ pooled, int first) {
    int wave = threadIdx.x >> 6, lane = threadIdx.x & 63;
    int r0 = blockIdx.x * 64 + wave * 16;
    if (r0 >= N_NODES) return;
    int g = lane >> 4;
    int c4 = (lane & 15) * 4;
    bool full = (r0 + 15 < N_NODES);
    bool fast = full && (batch_id[r0] == batch_id[r0 + 15]);
    float4 pacc = make_float4(0.f, 0.f, 0.f, 0.f);
#pragma unroll
    for (int i = 0; i < 4; ++i) {
        int row = r0 + i * 4 + g;
        if (row >= N_NODES) continue;
        int b = batch_id[row];
        float4 hv = *(const float4*)(h + (size_t)row * 64 + c4);
        float4 vv = *(const float4*)(vn + b * 64 + c4);
        float4 v;
        v.x = hv.x + vv.x; v.y = hv.y + vv.y; v.z = hv.z + vv.z; v.w = hv.w + vv.w;
        *(float4*)(h + (size_t)row * 64 + c4) = v;
        if (first) {
            *(float4*)(out + (size_t)row * 64 + c4) = v;
        } else {
            float4 o = *(const float4*)(out + (size_t)row * 64 + c4);
            o.x += v.x; o.y += v.y; o.z += v.z; o.w += v.w;
            *(float4*)(out + (size_t)row * 64 + c4) = o;
        }
        if (rbuf) {
            ushort4 rb;
            rb.x = f2bf(fmaxf(v.x, 0.f)); rb.y = f2bf(fmaxf(v.y, 0.f));
            rb.z = f2bf(fmaxf(v.z, 0.f)); rb.w = f2bf(fmaxf(v.w, 0.f));
            *(ushort4*)(rbuf + (size_t)row * 64 + c4) = rb;
        }
        if (pooled) {
            if (fast) {
                pacc.x += v.x; pacc.y += v.y; pacc.z += v.z; pacc.w += v.w;
            } else {
                atomicAdd(&pooled[b * 64 + c4 + 0], v.x);
                atomicAdd(&pooled[b * 64 + c4 + 1], v.y);
                atomicAdd(&pooled[b * 64 + c4 + 2], v.z);
                atomicAdd(&pooled[b * 64 + c4 + 3], v.w);
            }
        }
    }
    if (pooled && fast) {
        pacc.x += __shfl_xor(pacc.x, 16); pacc.x += __shfl_xor(pacc.x, 32);
        pacc.y += __shfl_xor(pacc.y, 16); pacc.y += __shfl_xor(pacc.y, 32);
        pacc.z += __shfl_xor(pacc.z, 16); pacc.z += __shfl_xor(pacc.z, 32);
        pacc.w += __shfl_xor(pacc.w, 16); pacc.w += __shfl_xor(pacc.w, 32);
        if (g == 0) {
            int b = batch_id[r0];
            atomicAdd(&pooled[b * 64 + c4 + 0], pacc.x);
            atomicAdd(&pooled[b * 64 + c4 + 1], pacc.y);
            atomicAdd(&pooled[b * 64 + c4 + 2], pacc.z);
            atomicAdd(&pooled[b * 64 + c4 + 3], pacc.w);
        }
    }
}

// input linear: out = in @ W + bias (mode 0 path of old k_gemm)
__global__ __launch_bounds__(256) void k_gemm0(
    const float* __restrict__ in, const float* __restrict__ W,
    const float* __restrict__ bias, float* __restrict__ out, int n) {
    __shared__ float sW[64 * 64];
    __shared__ float sIn[64 * 68];
    int tid = threadIdx.x;
    int row0 = blockIdx.x * 64;
#pragma unroll
    for (int i = 0; i < 4; ++i)
        ((float4*)sW)[tid + 256 * i] = ((const float4*)W)[tid + 256 * i];
#pragma unroll
    for (int i = 0; i < 4; ++i) {
        int idx = tid + 256 * i;
        int r = idx >> 4, j = idx & 15;
        float4 val = make_float4(0.f, 0.f, 0.f, 0.f);
        if (row0 + r < n) val = ((const float4*)in)[(size_t)(row0 + r) * 16 + j];
        ((float4*)(sIn + r * 68))[j] = val;
    }
    __syncthreads();
    int c4 = (tid & 15) * 4;
    int rl = (tid >> 4) * 4;
    float acc[4][4] = {{0.f}};
#pragma unroll 8
    for (int k = 0; k < 64; ++k) {
        float4 wv = *(const float4*)(sW + k * 64 + c4);
#pragma unroll
        for (int i = 0; i < 4; ++i) {
            float a = sIn[(rl + i) * 68 + k];
            acc[i][0] += a * wv.x; acc[i][1] += a * wv.y;
            acc[i][2] += a * wv.z; acc[i][3] += a * wv.w;
        }
    }
#pragma unroll
    for (int r = 0; r < 4; ++r) {
        int row = row0 + rl + r;
        if (row < n) {
            float4 o;
            o.x = acc[r][0] + bias[c4 + 0];
            o.y = acc[r][1] + bias[c4 + 1];
            o.z = acc[r][2] + bias[c4 + 2];
            o.w = acc[r][3] + bias[c4 + 3];
            *(float4*)(out + (size_t)row * 64 + c4) = o;
        }
    }
}

// Fused GIN stage 1: agg = (1+eps)h + CSR-gather(rbuf), then z1 = relu(BN1(agg@W1+b1))
__global__ __launch_bounds__(256) void k_gemm_agg(
    const float* __restrict__ h, const unsigned short* __restrict__ rbuf,
    const int* __restrict__ row_ptr, const unsigned short* __restrict__ csr_src,
    const float* __restrict__ eps, int l,
    const float* __restrict__ W, const float* __restrict__ bias,
    const float* __restrict__ g, const float* __restrict__ be,
    const float* __restrict__ m, const float* __restrict__ v,
    float* __restrict__ out) {
    __shared__ float sW[64 * 64];
    __shared__ float sIn[64 * 68];
    int tid = threadIdx.x;
    int row0 = blockIdx.x * 64;
    float se = 1.0f + eps[l];
#pragma unroll
    for (int i = 0; i < 4; ++i)
        ((float4*)sW)[tid + 256 * i] = ((const float4*)W)[tid + 256 * i];
#pragma unroll
    for (int i = 0; i < 4; ++i) {
        int idx = tid + 256 * i;
        int r = idx >> 4, j = idx & 15;
        float4 val = make_float4(0.f, 0.f, 0.f, 0.f);
        if (row0 + r < N_NODES) val = ((const float4*)h)[(size_t)(row0 + r) * 16 + j];
        val.x *= se; val.y *= se; val.z *= se; val.w *= se;
        ((float4*)(sIn + r * 68))[j] = val;
    }
    __syncthreads();
    // gather: wave w accumulates rows w*16 .. w*16+15 (lane = channel)
    int wv = tid >> 6, lane = tid & 63;
    for (int rr = 0; rr < 16; ++rr) {
        int node = row0 + wv * 16 + rr;
        if (node >= N_NODES) break;
        int s0 = row_ptr[node], s1 = row_ptr[node + 1];
        float acc = 0.f;
        for (int bb = s0; bb < s1; bb += 64) {
            int e = bb + lane;
            int sidx = (e < s1) ? (int)csr_src[e] : 0;
            int cnt = s1 - bb; if (cnt > 64) cnt = 64;
            int j = 0;
            for (; j + 3 < cnt; j += 4) {
                int a = __shfl(sidx, j), b2 = __shfl(sidx, j + 1);
                int c = __shfl(sidx, j + 2), d = __shfl(sidx, j + 3);
                float v0 = bf2f(rbuf[(size_t)a  * 64 + lane]);
                float v1 = bf2f(rbuf[(size_t)b2 * 64 + lane]);
                float v2 = bf2f(rbuf[(size_t)c  * 64 + lane]);
                float v3 = bf2f(rbuf[(size_t)d  * 64 + lane]);
                acc += (v0 + v1) + (v2 + v3);
            }
            for (; j < cnt; ++j) {
                int a = __shfl(sidx, j);
                acc += bf2f(rbuf[(size_t)a * 64 + lane]);
            }
        }
        sIn[(wv * 16 + rr) * 68 + lane] += acc;
    }
    __syncthreads();
    int c4 = (tid & 15) * 4;
    int rl = (tid >> 4) * 4;
    float acc[4][4] = {{0.f}};
#pragma unroll 8
    for (int k = 0; k < 64; ++k) {
        float4 wv4 = *(const float4*)(sW + k * 64 + c4);
#pragma unroll
        for (int i = 0; i < 4; ++i) {
            float a = sIn[(rl + i) * 68 + k];
            acc[i][0] += a * wv4.x; acc[i][1] += a * wv4.y;
            acc[i][2] += a * wv4.z; acc[i][3] += a * wv4.w;
        }
    }
    float scl[4], shf[4];
#pragma unroll
    for (int j = 0; j < 4; ++j) {
        int c = c4 + j;
        float sc = g[c] * rsqrtf(v[c] + 1e-5f);
        scl[j] = sc;
        shf[j] = be[c] - m[c] * sc + bias[c] * sc;
    }
#pragma unroll
    for (int r = 0; r < 4; ++r) {
        int row = row0 + rl + r;
        if (row < N_NODES) {
            float4 o;
            o.x = fmaxf(acc[r][0] * scl[0] + shf[0], 0.f);
            o.y = fmaxf(acc[r][1] * scl[1] + shf[1], 0.f);
            o.z = fmaxf(acc[r][2] * scl[2] + shf[2], 0.f);
            o.w = fmaxf(acc[r][3] * scl[3] + shf[3], 0.f);
            *(float4*)(out + (size_t)row * 64 + c4) = o;
        }
    }
}

// GIN stage 2 (z1@W2 -> BN -> relu -> h) + one extra block running the vn MLP
__global__ __launch_bounds__(256) void k_gemm_vn(
    const float* __restrict__ in, const float* __restrict__ W,
    const float* __restrict__ bias, const float* __restrict__ g,
    const float* __restrict__ be, const float* __restrict__ m,
    const float* __restrict__ v, float* __restrict__ out,
    const float* __restrict__ pooled,
    const float* __restrict__ W1, const float* __restrict__ b1,
    const float* __restrict__ g1, const float* __restrict__ be1,
    const float* __restrict__ m1, const float* __restrict__ v1,
    const float* __restrict__ W2, const float* __restrict__ b2,
    const float* __restrict__ g2, const float* __restrict__ be2,
    const float* __restrict__ m2, const float* __restrict__ v2,
    float* __restrict__ vn_out, float* __restrict__ pooled_out) {
    __shared__ float sW[64 * 64];
    __shared__ float sIn[64 * 68];
    int tid = threadIdx.x;
    int c4 = (tid & 15) * 4;
    int rl = (tid >> 4) * 4;

    if (blockIdx.x == GB) {
        // vn-MLP: two 64-row halves of pooled, two chained mini-GEMMs each
        for (int ph = 0; ph < 2; ++ph) {
#pragma unroll
            for (int i = 0; i < 4; ++i)
                ((float4*)sW)[tid + 256 * i] = ((const float4*)W1)[tid + 256 * i];
#pragma unroll
            for (int i = 0; i < 4; ++i) {
                int idx = tid + 256 * i;
                int r = idx >> 4, j = idx & 15;
                ((float4*)(sIn + r * 68))[j] = ((const float4*)pooled)[(ph * 64 + r) * 16 + j];
            }
            __syncthreads();
            float acc[4][4] = {{0.f}};
#pragma unroll 8
            for (int k = 0; k < 64; ++k) {
                float4 w = *(const float4*)(sW + k * 64 + c4);
#pragma unroll
                for (int i = 0; i < 4; ++i) {
                    float a = sIn[(rl + i) * 68 + k];
                    acc[i][0] += a * w.x; acc[i][1] += a * w.y;
                    acc[i][2] += a * w.z; acc[i][3] += a * w.w;
                }
            }
            float scl[4], shf[4];
#pragma unroll
            for (int j = 0; j < 4; ++j) {
                int c = c4 + j;
                float sc = g1[c] * rsqrtf(v1[c] + 1e-5f);
                scl[j] = sc;
                shf[j] = be1[c] - m1[c] * sc + b1[c] * sc;
            }
            __syncthreads();
#pragma unroll
            for (int i = 0; i < 4; ++i)
#pragma unroll
                for (int j = 0; j < 4; ++j)
                    sIn[(rl + i) * 68 + c4 + j] = fmaxf(acc[i][j] * scl[j] + shf[j], 0.f);
#pragma unroll
            for (int i = 0; i < 4; ++i)
                ((float4*)sW)[tid + 256 * i] = ((const float4*)W2)[tid + 256 * i];
            __syncthreads();
            float acc2[4][4] = {{0.f}};
#pragma unroll 8
            for (int k = 0; k < 64; ++k) {
                float4 w = *(const float4*)(sW + k * 64 + c4);
#pragma unroll
                for (int i = 0; i < 4; ++i) {
                    float a = sIn[(rl + i) * 68 + k];
                    acc2[i][0] += a * w.x; acc2[i][1] += a * w.y;
                    acc2[i][2] += a * w.z; acc2[i][3] += a * w.w;
                }
            }
#pragma unroll
            for (int j = 0; j < 4; ++j) {
                int c = c4 + j;
                float sc = g2[c] * rsqrtf(v2[c] + 1e-5f);
                scl[j] = sc;
                shf[j] = be2[c] - m2[c] * sc + b2[c] * sc;
            }
#pragma unroll
            for (int i = 0; i < 4; ++i) {
                int row = ph * 64 + rl + i;
                float4 o;
                o.x = fmaxf(acc2[i][0] * scl[0] + shf[0], 0.f);
                o.y = fmaxf(acc2[i][1] * scl[1] + shf[1], 0.f);
                o.z = fmaxf(acc2[i][2] * scl[2] + shf[2], 0.f);
                o.w = fmaxf(acc2[i][3] * scl[3] + shf[3], 0.f);
                *(float4*)(vn_out + row * 64 + c4) = o;
                *(float4*)(pooled_out + row * 64 + c4) = o;
            }
            __syncthreads();
        }
        return;
    }

    // regular path: out = relu(BN(in@W + bias))
    int row0 = blockIdx.x * 64;
#pragma unroll
    for (int i = 0; i < 4; ++i)
        ((float4*)sW)[tid + 256 * i] = ((const float4*)W)[tid + 256 * i];
#pragma unroll
    for (int i = 0; i < 4; ++i) {
        int idx = tid + 256 * i;
        int r = idx >> 4, j = idx & 15;
        float4 val = make_float4(0.f, 0.f, 0.f, 0.f);
        if (row0 + r < N_NODES) val = ((const float4*)in)[(size_t)(row0 + r) * 16 + j];
        ((float4*)(sIn + r * 68))[j] = val;
    }
    __syncthreads();
    float acc[4][4] = {{0.f}};
#pragma unroll 8
    for (int k = 0; k < 64; ++k) {
        float4 wv = *(const float4*)(sW + k * 64 + c4);
#pragma unroll
        for (int i = 0; i < 4; ++i) {
            float a = sIn[(rl + i) * 68 + k];
            acc[i][0] += a * wv.x; acc[i][1] += a * wv.y;
            acc[i][2] += a * wv.z; acc[i][3] += a * wv.w;
        }
    }
    float scl[4], shf[4];
#pragma unroll
    for (int j = 0; j < 4; ++j) {
        int c = c4 + j;
        float sc = g[c] * rsqrtf(v[c] + 1e-5f);
        scl[j] = sc;
        shf[j] = be[c] - m[c] * sc + bias[c] * sc;
    }
#pragma unroll
    for (int r = 0; r < 4; ++r) {
        int row = row0 + rl + r;
        if (row < N_NODES) {
            float4 o;
            o.x = fmaxf(acc[r][0] * scl[0] + shf[0], 0.f);
            o.y = fmaxf(acc[r][1] * scl[1] + shf[1], 0.f);
            o.z = fmaxf(acc[r][2] * scl[2] + shf[2], 0.f);
            o.w = fmaxf(acc[r][3] * scl[3] + shf[3], 0.f);
            *(float4*)(out + (size_t)row * 64 + c4) = o;
        }
    }
}

extern "C" void kernel_launch(void* const* d_in, const int* in_sizes, int n_in,
                              void* d_out, int out_size, void* d_ws, size_t ws_size,
                              hipStream_t stream) {
    const float* x      = (const float*)d_in[0];
    const float* lin_W  = (const float*)d_in[1];
    const float* lin_b  = (const float*)d_in[2];
    const float* eps    = (const float*)d_in[3];
    const float* gin_W1 = (const float*)d_in[4];
    const float* gin_b1 = (const float*)d_in[5];
    const float* gbn_g  = (const float*)d_in[6];
    const float* gbn_b  = (const float*)d_in[7];
    const float* gbn_m  = (const float*)d_in[8];
    const float* gbn_v  = (const float*)d_in[9];
    const float* gin_W2 = (const float*)d_in[10];
    const float* gin_b2 = (const float*)d_in[11];
    const float* bn_g   = (const float*)d_in[12];
    const float* bn_b   = (const float*)d_in[13];
    const float* bn_m   = (const float*)d_in[14];
    const float* bn_v   = (const float*)d_in[15];
    const float* vn_emb = (const float*)d_in[16];
    const float* vn_W1  = (const float*)d_in[17];
    const float* vn_b1  = (const float*)d_in[18];
    const float* v1g    = (const float*)d_in[19];
    const float* v1b    = (const float*)d_in[20];
    const float* v1m    = (const float*)d_in[21];
    const float* v1v    = (const float*)d_in[22];
    const float* vn_W2  = (const float*)d_in[23];
    const float* vn_b2  = (const float*)d_in[24];
    const float* v2g    = (const float*)d_in[25];
    const float* v2b    = (const float*)d_in[26];
    const float* v2m    = (const float*)d_in[27];
    const float* v2v    = (const float*)d_in[28];
    const int* src      = (const int*)d_in[29];
    const int* dst      = (const int*)d_in[30];
    const int* batch_id = (const int*)d_in[31];
    float* out = (float*)d_out;

    // workspace layout (16B-aligned regions)
    float* h      = (float*)d_ws;                          // N*64 f32
    float* z1     = h + (size_t)N_NODES * 64;              // N*64 f32
    unsigned short* rbuf = (unsigned short*)(z1 + (size_t)N_NODES * 64); // N*64 bf16
    float* vn     = (float*)(rbuf + (size_t)N_NODES * 64); // B*64
    float* pooled = vn + (size_t)NB * 64;                  // B*64
    int*   gcount  = (int*)(pooled + (size_t)NB * 64);     // NBUCK*P1B = 38416
    int*   row_ptr = gcount + NBUCK * P1B;                 // N+1
    unsigned* tmp  = (unsigned*)(row_ptr + N_NODES + 2);   // E u32
    unsigned short* csr_src = (unsigned short*)(tmp + N_EDGES); // E ushort

    // ---- CSR build (radix partition; single-owner final writes) ----
    k_p1hist<<<P1B, 256, 0, stream>>>(dst, gcount);
    k_p1scan<<<1, 256, 0, stream>>>(gcount, row_ptr);
    k_p1scat<<<P1B, 256, 0, stream>>>(src, dst, gcount, tmp);
    k_p2<<<NBUCK, 256, 0, stream>>>(tmp, gcount, row_ptr, csr_src);

    // input linear + vn/pooled init
    k_gemm0<<<GB, 256, 0, stream>>>(x, lin_W, lin_b, h, N_NODES);
    k_vn_init<<<32, 256, 0, stream>>>(vn_emb, vn, pooled);

    for (int l = 0; l < 4; ++l) {   // layer 4's GINConv output is never used
        k_pre<<<GB, 256, 0, stream>>>(h, vn, batch_id, out, rbuf, pooled, l == 0);
        k_gemm_agg<<<GB, 256, 0, stream>>>(h, rbuf, row_ptr, csr_src, eps, l,
                                           gin_W1 + l * 4096, gin_b1 + l * 64,
                                           gbn_g + l * 64, gbn_b + l * 64,
                                           gbn_m + l * 64, gbn_v + l * 64, z1);
        k_gemm_vn<<<GB + 1, 256, 0, stream>>>(z1, gin_W2 + l * 4096, gin_b2 + l * 64,
                                              bn_g + l * 64, bn_b + l * 64,
                                              bn_m + l * 64, bn_v + l * 64, h,
                                              pooled,
                                              vn_W1 + l * 4096, vn_b1 + l * 64,
                                              v1g + l * 64, v1b + l * 64,
                                              v1m + l * 64, v1v + l * 64,
                                              vn_W2 + l * 4096, vn_b2 + l * 64,
                                              v2g + l * 64, v2b + l * 64,
                                              v2m + l * 64, v2v + l * 64,
                                              vn, pooled);
    }
    // l = 4: only h += vn[batch]; out += h
    k_pre<<<GB, 256, 0, stream>>>(h, vn, batch_id, out, nullptr, nullptr, 0);
}